// Round 11
// baseline (298.713 us; speedup 1.0000x reference)
//
#include <hip/hip_runtime.h>

#define N_NODES_C 50000
#define N_EDGES_C 1600000
#define EPS_C 1e-5f

typedef __attribute__((ext_vector_type(8))) short bf16x8;
typedef __attribute__((ext_vector_type(8))) _Float16 f16x8;
typedef __attribute__((ext_vector_type(4))) float f32x4;

static __device__ __forceinline__ unsigned short rne_bf(float f) {
    union { float f; unsigned int u; } v; v.f = f;
    unsigned int r = v.u + 0x7fffu + ((v.u >> 16) & 1u);  // RNE
    return (unsigned short)(r >> 16);
}
static __device__ __forceinline__ float bf2f(unsigned short h) {
    union { unsigned int u; float f; } v; v.u = ((unsigned int)h) << 16;
    return v.f;
}
static __device__ __forceinline__ void splitf(float x, short& hi, short& lo) {
    unsigned short h = rne_bf(x);
    hi = (short)h;
    lo = (short)rne_bf(x - bf2f(h));
}
static __device__ __forceinline__ void ld8split(const float* p, float scale,
                                                bf16x8& hi, bf16x8& lo) {
    float4 a = *reinterpret_cast<const float4*>(p);
    float4 b = *reinterpret_cast<const float4*>(p + 4);
    float v[8] = {a.x, a.y, a.z, a.w, b.x, b.y, b.z, b.w};
#pragma unroll
    for (int i = 0; i < 8; ++i) {
        short h, l;
        splitf(v[i] * scale, h, l);
        hi[i] = h; lo[i] = l;
    }
}
static __device__ __forceinline__ short f2h(float f) {
    union { _Float16 h; short s; } u; u.h = (_Float16)f; return u.s;
}
// f32 -> f16x8 (8 hardware cvt)
static __device__ __forceinline__ f16x8 ld8h(const float* p) {
    float4 a = *reinterpret_cast<const float4*>(p);
    float4 b = *reinterpret_cast<const float4*>(p + 4);
    f16x8 r;
    r[0] = (_Float16)a.x; r[1] = (_Float16)a.y;
    r[2] = (_Float16)a.z; r[3] = (_Float16)a.w;
    r[4] = (_Float16)b.x; r[5] = (_Float16)b.y;
    r[6] = (_Float16)b.z; r[7] = (_Float16)b.w;
    return r;
}

#define MFMA3(acc, wh, wl, bh, bl)                                            \
    acc = __builtin_amdgcn_mfma_f32_16x16x32_bf16(wh, bh, acc, 0, 0, 0);      \
    acc = __builtin_amdgcn_mfma_f32_16x16x32_bf16(wl, bh, acc, 0, 0, 0);      \
    acc = __builtin_amdgcn_mfma_f32_16x16x32_bf16(wh, bl, acc, 0, 0, 0);

// ===========================================================================
// Pre-convert x (50000x32 f32) to a single fp16 plane (3.2 MB — L2-resident).
// ===========================================================================
__global__ __launch_bounds__(256) void prep_x_kernel(
    const float* __restrict__ x, unsigned short* __restrict__ xf)
{
    const int i = blockIdx.x * 256 + threadIdx.x;  // float4 index
    if (i >= (N_NODES_C * 32) / 4) return;
    float4 v = reinterpret_cast<const float4*>(x)[i];
    short4 h;
    h.x = f2h(v.x); h.y = f2h(v.y); h.z = f2h(v.z); h.w = f2h(v.w);
    reinterpret_cast<short4*>(xf)[i] = h;
}

// ===========================================================================
// Fold the 8 XCD-local accumulator copies
// ===========================================================================
__global__ __launch_bounds__(256) void reduce_kernel(
    const float* __restrict__ agg8, const float* __restrict__ cnt8,
    float* __restrict__ agg, float* __restrict__ cntf)
{
    const int i = blockIdx.x * 256 + threadIdx.x;
    if (i < N_NODES_C * 16) {
        float s = 0.f;
#pragma unroll
        for (int k = 0; k < 8; ++k) s += agg8[(size_t)k * (N_NODES_C * 16) + i];
        agg[i] = s;
    }
    if (i < N_NODES_C) {
        float s = 0.f;
#pragma unroll
        for (int k = 0; k < 8; ++k) s += cnt8[(size_t)k * N_NODES_C + i];
        cntf[i] = s;
    }
}

// ===========================================================================
// Edge MLP — R10 structure/numerics (fp16 single-plane, L2-resident gathers).
// LDS diet: layer-2 cross-wave partials stored f16 (19.7 KB total) ->
// 8 blocks/CU; grid 5000 x 10 iters for residency + tail.
// ===========================================================================
__global__ __launch_bounds__(256) void edge_kernel(
    const unsigned short* __restrict__ xf,
    const float* __restrict__ ea, const float* __restrict__ u,
    const int* __restrict__ src, const int* __restrict__ dst,
    const float* __restrict__ W1, const float* __restrict__ b1,
    const float* __restrict__ W2, const float* __restrict__ b2,
    const float* __restrict__ gamma, const float* __restrict__ beta,
    float* __restrict__ e_out, float* __restrict__ agg8, float* __restrict__ cnt8,
    float* __restrict__ esum)
{
    // per-wave hidden slab: [wave][edge-row 32][k-local 32 pad 40] f16
    __shared__ __attribute__((aligned(16))) unsigned short hs[4][32][40];
    // cross-wave layer-2 partials, f16, double-buffered (pad 18)
    __shared__ _Float16 red[2][4][32][18];
    __shared__ float esr[4][16];

    const int tid = threadIdx.x;
    const int w = tid >> 6, l = tid & 63, g = l >> 4, c = l & 15;
    const int csw = c >> 2;
    const int off8 = 8 * (g & 1);
    const bool glt2 = (g < 2);

    float* aggc = agg8 + (size_t)(blockIdx.x & 7) * (N_NODES_C * 16);
    float* cntc = cnt8 + (size_t)(blockIdx.x & 7) * N_NODES_C;

    // ---- W1 fragments (f16, single), K-permuted: kp -> orig row
    f16x8 w1f[3][2];
#pragma unroll
    for (int kk = 0; kk < 3; ++kk)
#pragma unroll
        for (int nt = 0; nt < 2; ++nt) {
            f16x8 h;
#pragma unroll
            for (int j = 0; j < 8; ++j) {
                const int kp = 32 * kk + 8 * g + j;
                const int orig = (kp < 16) ? kp
                               : (kp < 32) ? (64 + kp)
                                           : (kp - 16);
                h[j] = (_Float16)W1[(size_t)orig * 128 + 32 * w + 16 * nt + c];
            }
            w1f[kk][nt] = h;
        }

    // ---- W2 slice fragment (K rows [32w,32w+32)), f16
    f16x8 w2f;
#pragma unroll
    for (int j = 0; j < 8; ++j)
        w2f[j] = (_Float16)W2[(size_t)(32 * w + 8 * g + j) * 16 + c];

    // ---- hoisted u fragment (lanes g>=2 in kk0)
    f16x8 uf = ld8h(u + off8);

    float b1v[2][4];
#pragma unroll
    for (int nt = 0; nt < 2; ++nt)
#pragma unroll
        for (int r = 0; r < 4; ++r)
            b1v[nt][r] = b1[32 * w + 16 * nt + 4 * g + r];

    const int ecol = tid & 15;
    const float b2c = b2[ecol], gc = gamma[ecol], btc = beta[ecol];

    float esl = 0.f;
    const int base = blockIdx.x * 320;  // 5000 blocks * 10 iters * 32 edges

#pragma unroll 1
    for (int i = 0; i < 10; ++i) {
        const int ebase = base + i * 32;
        const int e0 = ebase + c, e1 = ebase + 16 + c;
        const size_t s0 = src[e0], s1 = src[e1];
        const size_t d0v = dst[e0], d1v = dst[e1];

        f32x4 acc[2][2];
#pragma unroll
        for (int t = 0; t < 2; ++t)
#pragma unroll
            for (int nt = 0; nt < 2; ++nt) {
                f32x4 z = {0.f, 0.f, 0.f, 0.f};
                acc[t][nt] = z;
            }

#pragma unroll
        for (int t = 0; t < 2; ++t) {
            const int et = (t ? e1 : e0);
            const size_t st = (t ? s1 : s0);
            const size_t dt = (t ? d1v : d0v);

            {   // kk=0: g<2 -> ea[e][8g] (cvt); g>=2 -> u (hoisted)
                f16x8 bv = glt2 ? ld8h(ea + (size_t)et * 16 + off8) : uf;
                acc[t][0] = __builtin_amdgcn_mfma_f32_16x16x32_f16(w1f[0][0], bv, acc[t][0], 0, 0, 0);
                acc[t][1] = __builtin_amdgcn_mfma_f32_16x16x32_f16(w1f[0][1], bv, acc[t][1], 0, 0, 0);
            }
            {   // kk=1: xs plane cols 8g (16B L2-hit gather)
                f16x8 bv = *reinterpret_cast<const f16x8*>(xf + st * 32 + 8 * g);
                acc[t][0] = __builtin_amdgcn_mfma_f32_16x16x32_f16(w1f[1][0], bv, acc[t][0], 0, 0, 0);
                acc[t][1] = __builtin_amdgcn_mfma_f32_16x16x32_f16(w1f[1][1], bv, acc[t][1], 0, 0, 0);
            }
            {   // kk=2: xd plane cols 8g
                f16x8 bv = *reinterpret_cast<const f16x8*>(xf + dt * 32 + 8 * g);
                acc[t][0] = __builtin_amdgcn_mfma_f32_16x16x32_f16(w1f[2][0], bv, acc[t][0], 0, 0, 0);
                acc[t][1] = __builtin_amdgcn_mfma_f32_16x16x32_f16(w1f[2][1], bv, acc[t][1], 0, 0, 0);
            }
        }

        // ---- bias + ReLU + f16 -> per-wave slab (swizzled)
#pragma unroll
        for (int t = 0; t < 2; ++t)
#pragma unroll
            for (int nt = 0; nt < 2; ++nt) {
                short4 h4;
                h4.x = f2h(fmaxf(acc[t][nt][0] + b1v[nt][0], 0.f));
                h4.y = f2h(fmaxf(acc[t][nt][1] + b1v[nt][1], 0.f));
                h4.z = f2h(fmaxf(acc[t][nt][2] + b1v[nt][2], 0.f));
                h4.w = f2h(fmaxf(acc[t][nt][3] + b1v[nt][3], 0.f));
                const int grp = ((2 * nt + (g >> 1)) ^ csw) * 8 + 4 * (g & 1);
                *reinterpret_cast<short4*>(&hs[w][16 * t + c][grp]) = h4;
            }

        // ---- layer 2 (this wave's K=32 slice), single f16 MFMA per tile
        f32x4 acc2[2];
#pragma unroll
        for (int t = 0; t < 2; ++t) { f32x4 z = {0.f, 0.f, 0.f, 0.f}; acc2[t] = z; }
#pragma unroll
        for (int t = 0; t < 2; ++t) {
            const int rg = (g ^ csw) * 8;
            f16x8 a2 = *reinterpret_cast<const f16x8*>(&hs[w][16 * t + c][rg]);
            acc2[t] = __builtin_amdgcn_mfma_f32_16x16x32_f16(a2, w2f, acc2[t], 0, 0, 0);
        }

        // ---- cross-wave partial reduce (f16 dbuf; one barrier per iter)
        const int ib = i & 1;
#pragma unroll
        for (int t = 0; t < 2; ++t)
#pragma unroll
            for (int r = 0; r < 4; ++r)
                red[ib][w][16 * t + 4 * g + r][c] = (_Float16)acc2[t][r];
        __syncthreads();

        // ---- epilogue: bias, ReLU, LN(16), store + XCD-local scatter
#pragma unroll
        for (int pass = 0; pass < 2; ++pass) {
            const int erow = (tid >> 4) + 16 * pass;  // 0..31
            float o = (float)red[ib][0][erow][ecol] + (float)red[ib][1][erow][ecol] +
                      (float)red[ib][2][erow][ecol] + (float)red[ib][3][erow][ecol] + b2c;
            o = fmaxf(o, 0.f);
            float s = o, q = o * o;
            s += __shfl_xor(s, 1);  q += __shfl_xor(q, 1);
            s += __shfl_xor(s, 2);  q += __shfl_xor(q, 2);
            s += __shfl_xor(s, 4);  q += __shfl_xor(q, 4);
            s += __shfl_xor(s, 8);  q += __shfl_xor(q, 8);
            const float mu = s * 0.0625f;
            const float var = fmaxf(q * 0.0625f - mu * mu, 0.f);
            const float val = (o - mu) * rsqrtf(var + EPS_C) * gc + btc;
            const int e2 = ebase + erow;
            e_out[(size_t)e2 * 16 + ecol] = val;
            const int d2 = dst[e2];
            atomicAdd(&aggc[(size_t)d2 * 16 + ecol], val);
            if (ecol == 0) atomicAdd(&cntc[d2], 1.f);
            esl += val;
        }
    }

    // ---- fused e_out column-sum
    esl += __shfl_xor(esl, 16);
    esl += __shfl_xor(esl, 32);
    if (l < 16) esr[w][c] = esl;
    __syncthreads();
    if (tid < 16) atomicAdd(&esum[tid], esr[0][tid] + esr[1][tid] + esr[2][tid] + esr[3][tid]);
}

// ===========================================================================
// Node MLP (unchanged, validated bf16 3-term). in[64]=[x(32), agg*rcp(16), u(16)]
// ===========================================================================
__global__ __launch_bounds__(256, 1) void node_kernel(
    const float* __restrict__ x, const float* __restrict__ u,
    const float* __restrict__ W1, const float* __restrict__ b1,
    const float* __restrict__ W2, const float* __restrict__ b2,
    const float* __restrict__ gamma, const float* __restrict__ beta,
    const float* __restrict__ agg, const float* __restrict__ cnt,
    float* __restrict__ x_out, float* __restrict__ xsum)
{
    __shared__ __attribute__((aligned(16))) unsigned short hs[4][32][2][40];
    __shared__ float red[4][32][36];
    __shared__ float xsr[4][32];

    const int tid = threadIdx.x;
    const int w = tid >> 6, l = tid & 63, g = l >> 4, c = l & 15;
    const int csw = c >> 2;

    bf16x8 w1h[2][2], w1l[2][2];
#pragma unroll
    for (int kk = 0; kk < 2; ++kk)
#pragma unroll
        for (int nt = 0; nt < 2; ++nt) {
            bf16x8 h, lo;
#pragma unroll
            for (int j = 0; j < 8; ++j) {
                float f = W1[(size_t)(32 * kk + 8 * g + j) * 128 + 32 * w + 16 * nt + c];
                short sh, sl; splitf(f, sh, sl);
                h[j] = sh; lo[j] = sl;
            }
            w1h[kk][nt] = h; w1l[kk][nt] = lo;
        }

    bf16x8 w2h[2], w2l[2];
#pragma unroll
    for (int n2 = 0; n2 < 2; ++n2) {
        bf16x8 h, lo;
#pragma unroll
        for (int j = 0; j < 8; ++j) {
            float f = W2[(size_t)(32 * w + 8 * g + j) * 32 + 16 * n2 + c];
            short sh, sl; splitf(f, sh, sl);
            h[j] = sh; lo[j] = sl;
        }
        w2h[n2] = h; w2l[n2] = lo;
    }

    float b1v[2][4];
#pragma unroll
    for (int nt = 0; nt < 2; ++nt)
#pragma unroll
        for (int r = 0; r < 4; ++r)
            b1v[nt][r] = b1[32 * w + 16 * nt + 4 * g + r];

    const int ncol = tid & 31;
    const float b2c = b2[ncol], gc = gamma[ncol], btc = beta[ncol];

    const int nbase = blockIdx.x * 32;
    const int n0 = min(nbase + c, N_NODES_C - 1);
    const int n1 = min(nbase + 16 + c, N_NODES_C - 1);
    const float rcp0 = 1.f / fmaxf(cnt[n0], 1.f);
    const float rcp1 = 1.f / fmaxf(cnt[n1], 1.f);

    f32x4 acc[2][2];
#pragma unroll
    for (int t = 0; t < 2; ++t)
#pragma unroll
        for (int nt = 0; nt < 2; ++nt) {
            f32x4 z = {0.f, 0.f, 0.f, 0.f};
            acc[t][nt] = z;
        }

    {
        bf16x8 bh0, bl0, bh1, bl1;
        ld8split(x + (size_t)n0 * 32 + 8 * g, 1.f, bh0, bl0);
        ld8split(x + (size_t)n1 * 32 + 8 * g, 1.f, bh1, bl1);
#pragma unroll
        for (int nt = 0; nt < 2; ++nt) {
            MFMA3(acc[0][nt], w1h[0][nt], w1l[0][nt], bh0, bl0);
            MFMA3(acc[1][nt], w1h[0][nt], w1l[0][nt], bh1, bl1);
        }
    }
    {
        const float* p0 = (g < 2) ? (agg + (size_t)n0 * 16 + 8 * g) : (u + 8 * (g - 2));
        const float* p1 = (g < 2) ? (agg + (size_t)n1 * 16 + 8 * g) : (u + 8 * (g - 2));
        const float sc0 = (g < 2) ? rcp0 : 1.f;
        const float sc1 = (g < 2) ? rcp1 : 1.f;
        bf16x8 bh0, bl0, bh1, bl1;
        ld8split(p0, sc0, bh0, bl0); ld8split(p1, sc1, bh1, bl1);
#pragma unroll
        for (int nt = 0; nt < 2; ++nt) {
            MFMA3(acc[0][nt], w1h[1][nt], w1l[1][nt], bh0, bl0);
            MFMA3(acc[1][nt], w1h[1][nt], w1l[1][nt], bh1, bl1);
        }
    }

#pragma unroll
    for (int t = 0; t < 2; ++t)
#pragma unroll
        for (int nt = 0; nt < 2; ++nt) {
            short4 hi4, lo4;
            float v0 = fmaxf(acc[t][nt][0] + b1v[nt][0], 0.f);
            float v1 = fmaxf(acc[t][nt][1] + b1v[nt][1], 0.f);
            float v2 = fmaxf(acc[t][nt][2] + b1v[nt][2], 0.f);
            float v3 = fmaxf(acc[t][nt][3] + b1v[nt][3], 0.f);
            splitf(v0, hi4.x, lo4.x); splitf(v1, hi4.y, lo4.y);
            splitf(v2, hi4.z, lo4.z); splitf(v3, hi4.w, lo4.w);
            const int grp = ((2 * nt + (g >> 1)) ^ csw) * 8 + 4 * (g & 1);
            *reinterpret_cast<short4*>(&hs[w][16 * t + c][0][grp]) = hi4;
            *reinterpret_cast<short4*>(&hs[w][16 * t + c][1][grp]) = lo4;
        }

    f32x4 acc2[2][2];
#pragma unroll
    for (int t = 0; t < 2; ++t)
#pragma unroll
        for (int n2 = 0; n2 < 2; ++n2) {
            f32x4 z = {0.f, 0.f, 0.f, 0.f};
            acc2[t][n2] = z;
        }
#pragma unroll
    for (int t = 0; t < 2; ++t) {
        const int rg = (g ^ csw) * 8;
        bf16x8 a2h = *reinterpret_cast<const bf16x8*>(&hs[w][16 * t + c][0][rg]);
        bf16x8 a2l = *reinterpret_cast<const bf16x8*>(&hs[w][16 * t + c][1][rg]);
#pragma unroll
        for (int n2 = 0; n2 < 2; ++n2) {
            acc2[t][n2] = __builtin_amdgcn_mfma_f32_16x16x32_bf16(a2h, w2h[n2], acc2[t][n2], 0, 0, 0);
            acc2[t][n2] = __builtin_amdgcn_mfma_f32_16x16x32_bf16(a2l, w2h[n2], acc2[t][n2], 0, 0, 0);
            acc2[t][n2] = __builtin_amdgcn_mfma_f32_16x16x32_bf16(a2h, w2l[n2], acc2[t][n2], 0, 0, 0);
        }
    }

#pragma unroll
    for (int t = 0; t < 2; ++t)
#pragma unroll
        for (int n2 = 0; n2 < 2; ++n2)
#pragma unroll
            for (int r = 0; r < 4; ++r)
                red[w][16 * t + 4 * g + r][16 * n2 + c] = acc2[t][n2][r];
    __syncthreads();

    float xsl = 0.f;
#pragma unroll
    for (int pass = 0; pass < 4; ++pass) {
        const int nrow = (tid >> 5) + 8 * pass;
        float o = red[0][nrow][ncol] + red[1][nrow][ncol] +
                  red[2][nrow][ncol] + red[3][nrow][ncol] + b2c;
        o = fmaxf(o, 0.f);
        float s = o, q = o * o;
        s += __shfl_xor(s, 1);   q += __shfl_xor(q, 1);
        s += __shfl_xor(s, 2);   q += __shfl_xor(q, 2);
        s += __shfl_xor(s, 4);   q += __shfl_xor(q, 4);
        s += __shfl_xor(s, 8);   q += __shfl_xor(q, 8);
        s += __shfl_xor(s, 16);  q += __shfl_xor(q, 16);
        const float mu = s * (1.f / 32.f);
        const float var = fmaxf(q * (1.f / 32.f) - mu * mu, 0.f);
        const float val = (o - mu) * rsqrtf(var + EPS_C) * gc + btc;
        const int node = nbase + nrow;
        if (node < N_NODES_C) {
            x_out[(size_t)node * 32 + ncol] = val;
            xsl += val;
        }
    }

    xsl += __shfl_xor(xsl, 32);
    if (l < 32) xsr[w][l] = xsl;
    __syncthreads();
    if (tid < 32) atomicAdd(&xsum[tid], xsr[0][tid] + xsr[1][tid] + xsr[2][tid] + xsr[3][tid]);
}

// ===========================================================================
// Global MLP (tiny, f32)
// ===========================================================================
__global__ __launch_bounds__(128) void global_kernel(
    const float* __restrict__ u,
    const float* __restrict__ W1, const float* __restrict__ b1,
    const float* __restrict__ W2, const float* __restrict__ b2,
    const float* __restrict__ esum, const float* __restrict__ xsum,
    float* __restrict__ u_out)
{
    __shared__ float gin[64];
    __shared__ float h[128];
    const int t = threadIdx.x;

    if (t < 16) gin[t] = u[t];
    else if (t < 48) gin[t] = xsum[t - 16] * (1.f / (float)N_NODES_C);
    else if (t < 64) gin[t] = esum[t - 48] * (1.f / (float)N_EDGES_C);
    __syncthreads();

    float hv = b1[t];
    for (int k = 0; k < 64; k++) hv = fmaf(gin[k], W1[(size_t)k * 128 + t], hv);
    h[t] = fmaxf(hv, 0.f);
    __syncthreads();

    if (t < 16) {
        float o = b2[t];
        for (int j = 0; j < 128; j++) o = fmaf(h[j], W2[(size_t)j * 16 + t], o);
        u_out[t] = fmaxf(o, 0.f);
    }
}

// ===========================================================================
extern "C" void kernel_launch(void* const* d_in, const int* in_sizes, int n_in,
                              void* d_out, int out_size, void* d_ws, size_t ws_size,
                              hipStream_t stream)
{
    const float* x    = (const float*)d_in[0];
    const float* ea   = (const float*)d_in[1];
    const float* u    = (const float*)d_in[2];
    const int*   src  = (const int*)d_in[3];
    const int*   dst  = (const int*)d_in[4];
    const float* eW1  = (const float*)d_in[5];
    const float* eb1  = (const float*)d_in[6];
    const float* eW2  = (const float*)d_in[7];
    const float* eb2  = (const float*)d_in[8];
    const float* eg   = (const float*)d_in[9];
    const float* ebt  = (const float*)d_in[10];
    const float* nW1  = (const float*)d_in[11];
    const float* nb1  = (const float*)d_in[12];
    const float* nW2  = (const float*)d_in[13];
    const float* nb2  = (const float*)d_in[14];
    const float* ng   = (const float*)d_in[15];
    const float* nbt  = (const float*)d_in[16];
    const float* gW1  = (const float*)d_in[17];
    const float* gb1  = (const float*)d_in[18];
    const float* gW2  = (const float*)d_in[19];
    const float* gb2  = (const float*)d_in[20];

    float* x_out = (float*)d_out;                              // 50000*32
    float* e_out = (float*)d_out + (size_t)N_NODES_C * 32;     // 1.6M*16
    float* u_out = e_out + (size_t)N_EDGES_C * 16;             // 16

    // ws layout (floats unless noted)
    float* agg8 = (float*)d_ws;                          // 8*800000 = 6.4M
    float* cnt8 = agg8 + (size_t)8 * 800000;             // 8*50000 = 400000
    float* esum = cnt8 + (size_t)8 * 50000;              // 16
    float* xsum = esum + 16;                             // 32
    float* agg  = xsum + 32;                             // 800000
    float* cntf = agg + 800000;                          // 50000
    unsigned short* xf = (unsigned short*)(cntf + 50000);  // 1.6M ushort (f16)

    // zero the atomic targets: agg8 + cnt8 + esum + xsum (contiguous)
    hipMemsetAsync(d_ws, 0,
                   ((size_t)8 * 800000 + 8 * 50000 + 48) * sizeof(float), stream);

    prep_x_kernel<<<(N_NODES_C * 32 / 4 + 255) / 256, 256, 0, stream>>>(x, xf);

    edge_kernel<<<5000, 256, 0, stream>>>(
        xf, ea, u, src, dst, eW1, eb1, eW2, eb2, eg, ebt,
        e_out, agg8, cnt8, esum);

    reduce_kernel<<<(N_NODES_C * 16 + 255) / 256, 256, 0, stream>>>(
        agg8, cnt8, agg, cntf);

    node_kernel<<<(N_NODES_C + 31) / 32, 256, 0, stream>>>(
        x, u, nW1, nb1, nW2, nb2, ng, nbt, agg, cntf, x_out, xsum);

    global_kernel<<<1, 128, 0, stream>>>(
        u, gW1, gb1, gW2, gb2, esum, xsum, u_out);
}

// Round 12
// 251.634 us; speedup vs baseline: 1.1871x; 1.1871x over previous
//
#include <hip/hip_runtime.h>

#define N_NODES_C 50000
#define N_EDGES_C 1600000
#define EPS_C 1e-5f

typedef __attribute__((ext_vector_type(8))) short bf16x8;
typedef __attribute__((ext_vector_type(8))) _Float16 f16x8;
typedef __attribute__((ext_vector_type(4))) float f32x4;

static __device__ __forceinline__ unsigned short rne_bf(float f) {
    union { float f; unsigned int u; } v; v.f = f;
    unsigned int r = v.u + 0x7fffu + ((v.u >> 16) & 1u);  // RNE
    return (unsigned short)(r >> 16);
}
static __device__ __forceinline__ float bf2f(unsigned short h) {
    union { unsigned int u; float f; } v; v.u = ((unsigned int)h) << 16;
    return v.f;
}
static __device__ __forceinline__ void splitf(float x, short& hi, short& lo) {
    unsigned short h = rne_bf(x);
    hi = (short)h;
    lo = (short)rne_bf(x - bf2f(h));
}
static __device__ __forceinline__ void ld8split(const float* p, float scale,
                                                bf16x8& hi, bf16x8& lo) {
    float4 a = *reinterpret_cast<const float4*>(p);
    float4 b = *reinterpret_cast<const float4*>(p + 4);
    float v[8] = {a.x, a.y, a.z, a.w, b.x, b.y, b.z, b.w};
#pragma unroll
    for (int i = 0; i < 8; ++i) {
        short h, l;
        splitf(v[i] * scale, h, l);
        hi[i] = h; lo[i] = l;
    }
}
static __device__ __forceinline__ short f2h(float f) {
    union { _Float16 h; short s; } u; u.h = (_Float16)f; return u.s;
}
// f32 -> f16x8 (8 hardware cvt)
static __device__ __forceinline__ f16x8 ld8h(const float* p) {
    float4 a = *reinterpret_cast<const float4*>(p);
    float4 b = *reinterpret_cast<const float4*>(p + 4);
    f16x8 r;
    r[0] = (_Float16)a.x; r[1] = (_Float16)a.y;
    r[2] = (_Float16)a.z; r[3] = (_Float16)a.w;
    r[4] = (_Float16)b.x; r[5] = (_Float16)b.y;
    r[6] = (_Float16)b.z; r[7] = (_Float16)b.w;
    return r;
}

#define MFMA3(acc, wh, wl, bh, bl)                                            \
    acc = __builtin_amdgcn_mfma_f32_16x16x32_bf16(wh, bh, acc, 0, 0, 0);      \
    acc = __builtin_amdgcn_mfma_f32_16x16x32_bf16(wl, bh, acc, 0, 0, 0);      \
    acc = __builtin_amdgcn_mfma_f32_16x16x32_bf16(wh, bl, acc, 0, 0, 0);

// ===========================================================================
// Pre-convert x (50000x32 f32) to a single fp16 plane (3.2 MB — L2-resident).
// ===========================================================================
__global__ __launch_bounds__(256) void prep_x_kernel(
    const float* __restrict__ x, unsigned short* __restrict__ xf)
{
    const int i = blockIdx.x * 256 + threadIdx.x;  // float4 index
    if (i >= (N_NODES_C * 32) / 4) return;
    float4 v = reinterpret_cast<const float4*>(x)[i];
    short4 h;
    h.x = f2h(v.x); h.y = f2h(v.y); h.z = f2h(v.z); h.w = f2h(v.w);
    reinterpret_cast<short4*>(xf)[i] = h;
}

// ===========================================================================
// Fold the 8 XCD-local accumulator copies
// ===========================================================================
__global__ __launch_bounds__(256) void reduce_kernel(
    const float* __restrict__ agg8, const float* __restrict__ cnt8,
    float* __restrict__ agg, float* __restrict__ cntf)
{
    const int i = blockIdx.x * 256 + threadIdx.x;
    if (i < N_NODES_C * 16) {
        float s = 0.f;
#pragma unroll
        for (int k = 0; k < 8; ++k) s += agg8[(size_t)k * (N_NODES_C * 16) + i];
        agg[i] = s;
    }
    if (i < N_NODES_C) {
        float s = 0.f;
#pragma unroll
        for (int k = 0; k < 8; ++k) s += cnt8[(size_t)k * N_NODES_C + i];
        cntf[i] = s;
    }
}

// ===========================================================================
// Edge MLP — barrier-free (R9 structure) x fp16 single-plane (R10 numerics).
// Each wave owns its 32-edge tiles end-to-end: W1 f16 frags in LDS, full
// hidden in 4 chunks of 32, layer-2 accumulated across chunks, LN in
// registers + 16-lane shuffles. NO in-loop __syncthreads — atomics are
// fire-and-forget, waves fully decoupled. XCD-local scatter atomics.
// K permuted to [ea(16),u(16),xs(32),xd(32)] (validated R6/R9).
// ===========================================================================
__global__ __launch_bounds__(256) void edge_kernel(
    const unsigned short* __restrict__ xf,
    const float* __restrict__ ea, const float* __restrict__ u,
    const int* __restrict__ src, const int* __restrict__ dst,
    const float* __restrict__ W1, const float* __restrict__ b1,
    const float* __restrict__ W2, const float* __restrict__ b2,
    const float* __restrict__ gamma, const float* __restrict__ beta,
    float* __restrict__ e_out, float* __restrict__ agg8, float* __restrict__ cnt8,
    float* __restrict__ esum)
{
    // W1 frags (f16): [kk(3)][nt(8)][lane(64)][j(8)] = 24576 B
    __shared__ __attribute__((aligned(16))) unsigned short w1f[3 * 8 * 64 * 8];
    // per-wave hidden chunk: [wave][edge-row 32][32 pad 40] f16 = 10240 B
    __shared__ __attribute__((aligned(16))) unsigned short hbuf[4][32][40];
    __shared__ float b1s[128];
    __shared__ float esr[4][16];

    const int tid = threadIdx.x;
    const int w = tid >> 6, l = tid & 63, g = l >> 4, c = l & 15;
    const int off8 = 8 * (g & 1);
    const bool glt2 = (g < 2);

    float* aggc = agg8 + (size_t)(blockIdx.x & 7) * (N_NODES_C * 16);
    float* cntc = cnt8 + (size_t)(blockIdx.x & 7) * N_NODES_C;

    // ---- stage W1 (K-permuted) f16 frag-ordered into LDS
    for (int it = 0; it < 48; ++it) {
        int flat = it * 256 + tid;            // = kp*128 + n
        int kp = flat >> 7, n = flat & 127;
        int orig = (kp < 16) ? kp : (kp < 32) ? (64 + kp) : (kp - 16);
        _Float16 f = (_Float16)W1[(size_t)orig * 128 + n];
        int kk = kp >> 5, gg = (kp >> 3) & 3, j = kp & 7, nt = n >> 4, cc = n & 15;
        int lane = 16 * gg + cc;
        reinterpret_cast<_Float16*>(w1f)[((kk * 8 + nt) * 64 + lane) * 8 + j] = f;
    }
    if (tid < 128) b1s[tid] = b1[tid];

    // ---- W2 full-K fragments (4 chunks), f16, registers
    f16x8 w2f[4];
#pragma unroll
    for (int ch = 0; ch < 4; ++ch) {
        f16x8 h;
#pragma unroll
        for (int j = 0; j < 8; ++j)
            h[j] = (_Float16)W2[(size_t)(32 * ch + 8 * g + j) * 16 + c];
        w2f[ch] = h;
    }

    // ---- hoisted u fragment (lanes g>=2 in kk0)
    f16x8 uf = ld8h(u + off8);

    const float b2c = b2[c], gc = gamma[c], btc = beta[c];

    __syncthreads();  // w1f/b1s ready — the only barrier before the tail

    float esl = 0.f;
    const int base = blockIdx.x * 640 + w * 160;  // 2500 blocks, 5 iters * 32/wave

#pragma unroll 1
    for (int i = 0; i < 5; ++i) {
        const int ebase = base + i * 32;
        const int e0 = ebase + c, e1 = ebase + 16 + c;
        const size_t s0 = src[e0], s1 = src[e1];
        const size_t d0 = dst[e0], d1 = dst[e1];

        // ---- gathers for both 16-edge tiles (live across all 4 chunks)
        f16x8 in[3][2];
        in[0][0] = glt2 ? ld8h(ea + (size_t)e0 * 16 + off8) : uf;
        in[0][1] = glt2 ? ld8h(ea + (size_t)e1 * 16 + off8) : uf;
        in[1][0] = *reinterpret_cast<const f16x8*>(xf + s0 * 32 + 8 * g);
        in[1][1] = *reinterpret_cast<const f16x8*>(xf + s1 * 32 + 8 * g);
        in[2][0] = *reinterpret_cast<const f16x8*>(xf + d0 * 32 + 8 * g);
        in[2][1] = *reinterpret_cast<const f16x8*>(xf + d1 * 32 + 8 * g);

        f32x4 acc2[2];
#pragma unroll
        for (int t = 0; t < 2; ++t) { f32x4 z = {0.f, 0.f, 0.f, 0.f}; acc2[t] = z; }

        // ---- hidden in 4 chunks of 32; layer2 accumulates across chunks
#pragma unroll
        for (int ch = 0; ch < 4; ++ch) {
            f32x4 a1[2][2];
#pragma unroll
            for (int t = 0; t < 2; ++t)
#pragma unroll
                for (int p = 0; p < 2; ++p) {
                    f32x4 z = {0.f, 0.f, 0.f, 0.f};
                    a1[t][p] = z;
                }

#pragma unroll
            for (int kk = 0; kk < 3; ++kk)
#pragma unroll
                for (int p = 0; p < 2; ++p) {
                    const int nt = 2 * ch + p;
                    f16x8 wv = *reinterpret_cast<const f16x8*>(
                        &w1f[((kk * 8 + nt) * 64 + l) * 8]);
                    a1[0][p] = __builtin_amdgcn_mfma_f32_16x16x32_f16(wv, in[kk][0], a1[0][p], 0, 0, 0);
                    a1[1][p] = __builtin_amdgcn_mfma_f32_16x16x32_f16(wv, in[kk][1], a1[1][p], 0, 0, 0);
                }

            // bias + ReLU + f16 -> per-wave chunk slab
#pragma unroll
            for (int t = 0; t < 2; ++t)
#pragma unroll
                for (int p = 0; p < 2; ++p) {
                    float4 bb = *reinterpret_cast<const float4*>(
                        &b1s[16 * (2 * ch + p) + 4 * g]);
                    short4 h4;
                    h4.x = f2h(fmaxf(a1[t][p][0] + bb.x, 0.f));
                    h4.y = f2h(fmaxf(a1[t][p][1] + bb.y, 0.f));
                    h4.z = f2h(fmaxf(a1[t][p][2] + bb.z, 0.f));
                    h4.w = f2h(fmaxf(a1[t][p][3] + bb.w, 0.f));
                    *reinterpret_cast<short4*>(&hbuf[w][16 * t + c][16 * p + 4 * g]) = h4;
                }

            // layer2: this chunk's K=32 slice (wave-synchronous LDS, no barrier)
#pragma unroll
            for (int t = 0; t < 2; ++t) {
                f16x8 a2 = *reinterpret_cast<const f16x8*>(&hbuf[w][16 * t + c][8 * g]);
                acc2[t] = __builtin_amdgcn_mfma_f32_16x16x32_f16(a2, w2f[ch], acc2[t], 0, 0, 0);
            }
        }

        // ---- epilogue (per-wave, in-register): bias, ReLU, LN(16), stores
#pragma unroll
        for (int t = 0; t < 2; ++t)
#pragma unroll
            for (int r = 0; r < 4; ++r) {
                float o = fmaxf(acc2[t][r] + b2c, 0.f);
                float s = o, q = o * o;
                s += __shfl_xor(s, 1);  q += __shfl_xor(q, 1);
                s += __shfl_xor(s, 2);  q += __shfl_xor(q, 2);
                s += __shfl_xor(s, 4);  q += __shfl_xor(q, 4);
                s += __shfl_xor(s, 8);  q += __shfl_xor(q, 8);
                const float mu = s * 0.0625f;
                const float var = fmaxf(q * 0.0625f - mu * mu, 0.f);
                const float val = (o - mu) * rsqrtf(var + EPS_C) * gc + btc;
                const int erow = ebase + 16 * t + 4 * g + r;
                e_out[(size_t)erow * 16 + c] = val;
                const int d2 = dst[erow];
                atomicAdd(&aggc[(size_t)d2 * 16 + c], val);
                if (c == 0) atomicAdd(&cntc[d2], 1.f);
                esl += val;
            }
    }

    // ---- fused e_out column-sum
    esl += __shfl_xor(esl, 16);
    esl += __shfl_xor(esl, 32);
    if (l < 16) esr[w][c] = esl;
    __syncthreads();
    if (tid < 16) atomicAdd(&esum[tid], esr[0][tid] + esr[1][tid] + esr[2][tid] + esr[3][tid]);
}

// ===========================================================================
// Node MLP (unchanged, validated bf16 3-term). in[64]=[x(32), agg*rcp(16), u(16)]
// ===========================================================================
__global__ __launch_bounds__(256, 1) void node_kernel(
    const float* __restrict__ x, const float* __restrict__ u,
    const float* __restrict__ W1, const float* __restrict__ b1,
    const float* __restrict__ W2, const float* __restrict__ b2,
    const float* __restrict__ gamma, const float* __restrict__ beta,
    const float* __restrict__ agg, const float* __restrict__ cnt,
    float* __restrict__ x_out, float* __restrict__ xsum)
{
    __shared__ __attribute__((aligned(16))) unsigned short hs[4][32][2][40];
    __shared__ float red[4][32][36];
    __shared__ float xsr[4][32];

    const int tid = threadIdx.x;
    const int w = tid >> 6, l = tid & 63, g = l >> 4, c = l & 15;
    const int csw = c >> 2;

    bf16x8 w1h[2][2], w1l[2][2];
#pragma unroll
    for (int kk = 0; kk < 2; ++kk)
#pragma unroll
        for (int nt = 0; nt < 2; ++nt) {
            bf16x8 h, lo;
#pragma unroll
            for (int j = 0; j < 8; ++j) {
                float f = W1[(size_t)(32 * kk + 8 * g + j) * 128 + 32 * w + 16 * nt + c];
                short sh, sl; splitf(f, sh, sl);
                h[j] = sh; lo[j] = sl;
            }
            w1h[kk][nt] = h; w1l[kk][nt] = lo;
        }

    bf16x8 w2h[2], w2l[2];
#pragma unroll
    for (int n2 = 0; n2 < 2; ++n2) {
        bf16x8 h, lo;
#pragma unroll
        for (int j = 0; j < 8; ++j) {
            float f = W2[(size_t)(32 * w + 8 * g + j) * 32 + 16 * n2 + c];
            short sh, sl; splitf(f, sh, sl);
            h[j] = sh; lo[j] = sl;
        }
        w2h[n2] = h; w2l[n2] = lo;
    }

    float b1v[2][4];
#pragma unroll
    for (int nt = 0; nt < 2; ++nt)
#pragma unroll
        for (int r = 0; r < 4; ++r)
            b1v[nt][r] = b1[32 * w + 16 * nt + 4 * g + r];

    const int ncol = tid & 31;
    const float b2c = b2[ncol], gc = gamma[ncol], btc = beta[ncol];

    const int nbase = blockIdx.x * 32;
    const int n0 = min(nbase + c, N_NODES_C - 1);
    const int n1 = min(nbase + 16 + c, N_NODES_C - 1);
    const float rcp0 = 1.f / fmaxf(cnt[n0], 1.f);
    const float rcp1 = 1.f / fmaxf(cnt[n1], 1.f);

    f32x4 acc[2][2];
#pragma unroll
    for (int t = 0; t < 2; ++t)
#pragma unroll
        for (int nt = 0; nt < 2; ++nt) {
            f32x4 z = {0.f, 0.f, 0.f, 0.f};
            acc[t][nt] = z;
        }

    {
        bf16x8 bh0, bl0, bh1, bl1;
        ld8split(x + (size_t)n0 * 32 + 8 * g, 1.f, bh0, bl0);
        ld8split(x + (size_t)n1 * 32 + 8 * g, 1.f, bh1, bl1);
#pragma unroll
        for (int nt = 0; nt < 2; ++nt) {
            MFMA3(acc[0][nt], w1h[0][nt], w1l[0][nt], bh0, bl0);
            MFMA3(acc[1][nt], w1h[0][nt], w1l[0][nt], bh1, bl1);
        }
    }
    {
        const float* p0 = (g < 2) ? (agg + (size_t)n0 * 16 + 8 * g) : (u + 8 * (g - 2));
        const float* p1 = (g < 2) ? (agg + (size_t)n1 * 16 + 8 * g) : (u + 8 * (g - 2));
        const float sc0 = (g < 2) ? rcp0 : 1.f;
        const float sc1 = (g < 2) ? rcp1 : 1.f;
        bf16x8 bh0, bl0, bh1, bl1;
        ld8split(p0, sc0, bh0, bl0); ld8split(p1, sc1, bh1, bl1);
#pragma unroll
        for (int nt = 0; nt < 2; ++nt) {
            MFMA3(acc[0][nt], w1h[1][nt], w1l[1][nt], bh0, bl0);
            MFMA3(acc[1][nt], w1h[1][nt], w1l[1][nt], bh1, bl1);
        }
    }

#pragma unroll
    for (int t = 0; t < 2; ++t)
#pragma unroll
        for (int nt = 0; nt < 2; ++nt) {
            short4 hi4, lo4;
            float v0 = fmaxf(acc[t][nt][0] + b1v[nt][0], 0.f);
            float v1 = fmaxf(acc[t][nt][1] + b1v[nt][1], 0.f);
            float v2 = fmaxf(acc[t][nt][2] + b1v[nt][2], 0.f);
            float v3 = fmaxf(acc[t][nt][3] + b1v[nt][3], 0.f);
            splitf(v0, hi4.x, lo4.x); splitf(v1, hi4.y, lo4.y);
            splitf(v2, hi4.z, lo4.z); splitf(v3, hi4.w, lo4.w);
            const int grp = ((2 * nt + (g >> 1)) ^ csw) * 8 + 4 * (g & 1);
            *reinterpret_cast<short4*>(&hs[w][16 * t + c][0][grp]) = hi4;
            *reinterpret_cast<short4*>(&hs[w][16 * t + c][1][grp]) = lo4;
        }

    f32x4 acc2[2][2];
#pragma unroll
    for (int t = 0; t < 2; ++t)
#pragma unroll
        for (int n2 = 0; n2 < 2; ++n2) {
            f32x4 z = {0.f, 0.f, 0.f, 0.f};
            acc2[t][n2] = z;
        }
#pragma unroll
    for (int t = 0; t < 2; ++t) {
        const int rg = (g ^ csw) * 8;
        bf16x8 a2h = *reinterpret_cast<const bf16x8*>(&hs[w][16 * t + c][0][rg]);
        bf16x8 a2l = *reinterpret_cast<const bf16x8*>(&hs[w][16 * t + c][1][rg]);
#pragma unroll
        for (int n2 = 0; n2 < 2; ++n2) {
            acc2[t][n2] = __builtin_amdgcn_mfma_f32_16x16x32_bf16(a2h, w2h[n2], acc2[t][n2], 0, 0, 0);
            acc2[t][n2] = __builtin_amdgcn_mfma_f32_16x16x32_bf16(a2l, w2h[n2], acc2[t][n2], 0, 0, 0);
            acc2[t][n2] = __builtin_amdgcn_mfma_f32_16x16x32_bf16(a2h, w2l[n2], acc2[t][n2], 0, 0, 0);
        }
    }

#pragma unroll
    for (int t = 0; t < 2; ++t)
#pragma unroll
        for (int n2 = 0; n2 < 2; ++n2)
#pragma unroll
            for (int r = 0; r < 4; ++r)
                red[w][16 * t + 4 * g + r][16 * n2 + c] = acc2[t][n2][r];
    __syncthreads();

    float xsl = 0.f;
#pragma unroll
    for (int pass = 0; pass < 4; ++pass) {
        const int nrow = (tid >> 5) + 8 * pass;
        float o = red[0][nrow][ncol] + red[1][nrow][ncol] +
                  red[2][nrow][ncol] + red[3][nrow][ncol] + b2c;
        o = fmaxf(o, 0.f);
        float s = o, q = o * o;
        s += __shfl_xor(s, 1);   q += __shfl_xor(q, 1);
        s += __shfl_xor(s, 2);   q += __shfl_xor(q, 2);
        s += __shfl_xor(s, 4);   q += __shfl_xor(q, 4);
        s += __shfl_xor(s, 8);   q += __shfl_xor(q, 8);
        s += __shfl_xor(s, 16);  q += __shfl_xor(q, 16);
        const float mu = s * (1.f / 32.f);
        const float var = fmaxf(q * (1.f / 32.f) - mu * mu, 0.f);
        const float val = (o - mu) * rsqrtf(var + EPS_C) * gc + btc;
        const int node = nbase + nrow;
        if (node < N_NODES_C) {
            x_out[(size_t)node * 32 + ncol] = val;
            xsl += val;
        }
    }

    xsl += __shfl_xor(xsl, 32);
    if (l < 32) xsr[w][l] = xsl;
    __syncthreads();
    if (tid < 32) atomicAdd(&xsum[tid], xsr[0][tid] + xsr[1][tid] + xsr[2][tid] + xsr[3][tid]);
}

// ===========================================================================
// Global MLP (tiny, f32)
// ===========================================================================
__global__ __launch_bounds__(128) void global_kernel(
    const float* __restrict__ u,
    const float* __restrict__ W1, const float* __restrict__ b1,
    const float* __restrict__ W2, const float* __restrict__ b2,
    const float* __restrict__ esum, const float* __restrict__ xsum,
    float* __restrict__ u_out)
{
    __shared__ float gin[64];
    __shared__ float h[128];
    const int t = threadIdx.x;

    if (t < 16) gin[t] = u[t];
    else if (t < 48) gin[t] = xsum[t - 16] * (1.f / (float)N_NODES_C);
    else if (t < 64) gin[t] = esum[t - 48] * (1.f / (float)N_EDGES_C);
    __syncthreads();

    float hv = b1[t];
    for (int k = 0; k < 64; k++) hv = fmaf(gin[k], W1[(size_t)k * 128 + t], hv);
    h[t] = fmaxf(hv, 0.f);
    __syncthreads();

    if (t < 16) {
        float o = b2[t];
        for (int j = 0; j < 128; j++) o = fmaf(h[j], W2[(size_t)j * 16 + t], o);
        u_out[t] = fmaxf(o, 0.f);
    }
}

// ===========================================================================
extern "C" void kernel_launch(void* const* d_in, const int* in_sizes, int n_in,
                              void* d_out, int out_size, void* d_ws, size_t ws_size,
                              hipStream_t stream)
{
    const float* x    = (const float*)d_in[0];
    const float* ea   = (const float*)d_in[1];
    const float* u    = (const float*)d_in[2];
    const int*   src  = (const int*)d_in[3];
    const int*   dst  = (const int*)d_in[4];
    const float* eW1  = (const float*)d_in[5];
    const float* eb1  = (const float*)d_in[6];
    const float* eW2  = (const float*)d_in[7];
    const float* eb2  = (const float*)d_in[8];
    const float* eg   = (const float*)d_in[9];
    const float* ebt  = (const float*)d_in[10];
    const float* nW1  = (const float*)d_in[11];
    const float* nb1  = (const float*)d_in[12];
    const float* nW2  = (const float*)d_in[13];
    const float* nb2  = (const float*)d_in[14];
    const float* ng   = (const float*)d_in[15];
    const float* nbt  = (const float*)d_in[16];
    const float* gW1  = (const float*)d_in[17];
    const float* gb1  = (const float*)d_in[18];
    const float* gW2  = (const float*)d_in[19];
    const float* gb2  = (const float*)d_in[20];

    float* x_out = (float*)d_out;                              // 50000*32
    float* e_out = (float*)d_out + (size_t)N_NODES_C * 32;     // 1.6M*16
    float* u_out = e_out + (size_t)N_EDGES_C * 16;             // 16

    // ws layout (floats unless noted)
    float* agg8 = (float*)d_ws;                          // 8*800000 = 6.4M
    float* cnt8 = agg8 + (size_t)8 * 800000;             // 8*50000 = 400000
    float* esum = cnt8 + (size_t)8 * 50000;              // 16
    float* xsum = esum + 16;                             // 32
    float* agg  = xsum + 32;                             // 800000
    float* cntf = agg + 800000;                          // 50000
    unsigned short* xf = (unsigned short*)(cntf + 50000);  // 1.6M ushort (f16)

    // zero the atomic targets: agg8 + cnt8 + esum + xsum (contiguous)
    hipMemsetAsync(d_ws, 0,
                   ((size_t)8 * 800000 + 8 * 50000 + 48) * sizeof(float), stream);

    prep_x_kernel<<<(N_NODES_C * 32 / 4 + 255) / 256, 256, 0, stream>>>(x, xf);

    edge_kernel<<<2500, 256, 0, stream>>>(
        xf, ea, u, src, dst, eW1, eb1, eW2, eb2, eg, ebt,
        e_out, agg8, cnt8, esum);

    reduce_kernel<<<(N_NODES_C * 16 + 255) / 256, 256, 0, stream>>>(
        agg8, cnt8, agg, cntf);

    node_kernel<<<(N_NODES_C + 31) / 32, 256, 0, stream>>>(
        x, u, nW1, nb1, nW2, nb2, ng, nbt, agg, cntf, x_out, xsum);

    global_kernel<<<1, 128, 0, stream>>>(
        u, gW1, gb1, gW2, gb2, esum, xsum, u_out);
}